// Round 13
// baseline (47.184 us; speedup 1.0000x reference)
//
#include <hip/hip_runtime.h>
#include <hip/hip_bf16.h>

#define TT 2048
#define HH 1024
#define NTAGS 74
#define NPAD 80
#define CHK 32            // K elements per chunk
#define NCH (HH / CHK)    // 32 chunks
#define MROWS 128         // rows per block (wave = 32 rows = 2 row-tiles)
#define THREADS 256
#define NXCD 8

typedef __bf16 bf16x8 __attribute__((ext_vector_type(8)));
typedef float f32x4 __attribute__((ext_vector_type(4)));

// Transpose + convert W_out [1024][74] f32 -> Wt [80][1024] bf16 (pad cols 74..79 = 0)
__global__ __launch_bounds__(256) void prep_w_kernel(const float* __restrict__ W,
                                                     __bf16* __restrict__ Wt) {
    __shared__ float tile[64][80];
    const int k0 = blockIdx.x * 64;
    const int tid = threadIdx.x;
    for (int i = tid; i < 64 * NTAGS; i += 256) {
        int k = i / NTAGS, n = i - k * NTAGS;
        tile[k][n] = W[(k0 + k) * NTAGS + n];
    }
    __syncthreads();
    for (int i = tid; i < NPAD * 64; i += 256) {
        int n = i >> 6, kk = i & 63;
        float v = (n < NTAGS) ? tile[kk][n] : 0.0f;
        Wt[n * HH + k0 + kk] = (__bf16)v;
    }
}

// R13 = R5 pipeline + W-amortization geometry. Block = 256 thr (4 waves),
// M=128 rows, wave = 32 rows (2 row-tiles) x full K, CHK=32, grid 256.
// Per chunk per wave: 2 A-frag + 5 W-frag ds_reads feed 10 MFMA (W shared
// across row-tiles). Per 128 rows vs R5: W ds_reads 1280->640, W LDS bytes
// and W L2 traffic halved; A path, MFMA, barriers/CU, VMEM bytes conserved.
// LDS: A[3] @ 0 (3*8192), W[2] @ 24576 (2*5120) = 34816 B. Swizzle:
// byte = (row*64 + piece*16) ^ ((row&7)<<4), same family for writes+reads.
// Pipeline per R5: commit regs(ch+1) -> issue loads(ch+2) -> MFMA(ch) -> bar.
// Fully-invalid blocks (rowbase past length) early-exit writing bias.
__global__ __launch_bounds__(256, 2) void slu_main(const float* __restrict__ out_char,
                                                   const float* __restrict__ out_word,
                                                   const int* __restrict__ word_idx,
                                                   const int* __restrict__ is_head,
                                                   const int* __restrict__ valid_mask,
                                                   const __bf16* __restrict__ Wt,
                                                   const float* __restrict__ b_out,
                                                   float* __restrict__ out) {
    __shared__ __align__(16) char smem[34816];
    const int tid = threadIdx.x;
    const int wv = tid >> 6;
    const int lane = tid & 63;
    const int l15 = lane & 15;
    const int kgrp = lane >> 4;

    // ---- XCD-aware bijective swizzle (256 blocks = 8 XCDs x 32 chunks) ----
    const int bid = blockIdx.x;
    const int rb = (bid & (NXCD - 1)) * (256 / NXCD) + (bid >> 3);
    const int rowbase = rb * MROWS;
    const int batch = rowbase >> 11;  // T = 2048
    const size_t batbase = (size_t)batch * TT;

    // ---- early-exit: fully-invalid block writes bias and returns ----
    const int myv = (tid < MROWS) ? valid_mask[rowbase + tid] : 0;
    if (!__syncthreads_or(myv)) {
        for (int i = tid; i < MROWS * NTAGS; i += THREADS) {
            const int rr = i / NTAGS, cc = i - rr * NTAGS;
            out[(size_t)(rowbase + rr) * NTAGS + cc] = b_out[cc];
        }
        return;
    }

    // ---- A staging: thread covers row srow=tid>>1, 16-f32 half qh=tid&1 ----
    const int srow = tid >> 1;
    const int qh = tid & 1;
    const int r = rowbase + srow;
    const int widx = word_idx[r];
    const int val = valid_mask[r];
    const float rt = is_head[r] ? 0.88f : 0.70f;
    const float rate = val ? rt : 0.0f;
    const float crate = val ? (1.0f - rt) : 0.0f;
    const float* cptr = out_char + (size_t)r * HH + qh * 16;
    const float* wptr = out_word + (batbase + widx) * HH + qh * 16;
    const int akey = (srow & 7) << 4;
    const int awr0 = (srow * 64 + qh * 32) ^ akey;
    const int awr1 = (srow * 64 + qh * 32 + 16) ^ akey;

    // ---- W staging: 320 16B-units/chunk; thread covers unit tid, (tid<64)?256+tid ----
    const int wn0 = tid >> 2, wsu = tid & 3;
    const __bf16* wgp0 = Wt + (size_t)wn0 * HH + wsu * 8;
    const __bf16* wgp1 = wgp0 + 64 * HH;            // rows 64..79 (tid<64)
    const int wwr0 = (wn0 * 64 + wsu * 16) ^ ((wn0 & 7) << 4);
    const int wwr1 = ((wn0 + 64) * 64 + wsu * 16) ^ ((wn0 & 7) << 4);
    const bool w2 = (tid < 64);

    // ---- fragment read offsets (same swizzle family; row&7 == l15&7) ----
    const int fkey = (l15 & 7) << 4;
    int aoff[2], woff[5];
#pragma unroll
    for (int s = 0; s < 2; ++s)
        aoff[s] = ((wv * 32 + s * 16 + l15) * 64 + kgrp * 16) ^ fkey;
#pragma unroll
    for (int nt = 0; nt < 5; ++nt)
        woff[nt] = ((nt * 16 + l15) * 64 + kgrp * 16) ^ fkey;

    f32x4 acc[2][5];
#pragma unroll
    for (int s = 0; s < 2; ++s)
#pragma unroll
        for (int nt = 0; nt < 5; ++nt) acc[s][nt] = (f32x4){0.f, 0.f, 0.f, 0.f};

    float4 ac[4], aw[4];   // held A loads (chunk ch+2): 16 f32 each input
    bf16x8 wreg0, wreg1;

    // ---- prologue: stage chunk 0 directly; prefetch chunk 1 into regs ----
    {
        float4 c0[4], w0[4];
        if (val) {
#pragma unroll
            for (int i = 0; i < 4; ++i) {
                c0[i] = *(const float4*)(cptr + i * 4);
                w0[i] = *(const float4*)(wptr + i * 4);
            }
        }
        bf16x8 wr0 = *(const bf16x8*)(wgp0);
        bf16x8 wr1 = w2 ? *(const bf16x8*)(wgp1) : (bf16x8)0;
        bf16x8 f0, f1;
        if (val) {
#pragma unroll
            for (int i = 0; i < 2; ++i) {
                f0[i * 4 + 0] = (__bf16)(w0[i].x * rate + c0[i].x * crate);
                f0[i * 4 + 1] = (__bf16)(w0[i].y * rate + c0[i].y * crate);
                f0[i * 4 + 2] = (__bf16)(w0[i].z * rate + c0[i].z * crate);
                f0[i * 4 + 3] = (__bf16)(w0[i].w * rate + c0[i].w * crate);
                f1[i * 4 + 0] = (__bf16)(w0[i + 2].x * rate + c0[i + 2].x * crate);
                f1[i * 4 + 1] = (__bf16)(w0[i + 2].y * rate + c0[i + 2].y * crate);
                f1[i * 4 + 2] = (__bf16)(w0[i + 2].z * rate + c0[i + 2].z * crate);
                f1[i * 4 + 3] = (__bf16)(w0[i + 2].w * rate + c0[i + 2].w * crate);
            }
        } else {
            f0 = (bf16x8)0; f1 = (bf16x8)0;
        }
        *(bf16x8*)(smem + awr0) = f0;
        *(bf16x8*)(smem + awr1) = f1;
        *(bf16x8*)(smem + 24576 + wwr0) = wr0;
        if (w2) *(bf16x8*)(smem + 24576 + wwr1) = wr1;
        // prefetch chunk 1 into regs
        if (val) {
#pragma unroll
            for (int i = 0; i < 4; ++i) {
                ac[i] = *(const float4*)(cptr + CHK + i * 4);
                aw[i] = *(const float4*)(wptr + CHK + i * 4);
            }
        }
        wreg0 = *(const bf16x8*)(wgp0 + CHK);
        wreg1 = w2 ? *(const bf16x8*)(wgp1 + CHK) : (bf16x8)0;
    }
    __syncthreads();

    // ---- main loop ----
    for (int ch = 0; ch < NCH; ++ch) {
        // 1) commit prefetched chunk ch+1 to LDS
        if (ch + 1 < NCH) {
            char* An = smem + ((ch + 1) % 3) * 8192;
            char* Wn = smem + 24576 + ((ch + 1) & 1) * 5120;
            bf16x8 f0, f1;
            if (val) {
#pragma unroll
                for (int i = 0; i < 2; ++i) {
                    f0[i * 4 + 0] = (__bf16)(aw[i].x * rate + ac[i].x * crate);
                    f0[i * 4 + 1] = (__bf16)(aw[i].y * rate + ac[i].y * crate);
                    f0[i * 4 + 2] = (__bf16)(aw[i].z * rate + ac[i].z * crate);
                    f0[i * 4 + 3] = (__bf16)(aw[i].w * rate + ac[i].w * crate);
                    f1[i * 4 + 0] = (__bf16)(aw[i + 2].x * rate + ac[i + 2].x * crate);
                    f1[i * 4 + 1] = (__bf16)(aw[i + 2].y * rate + ac[i + 2].y * crate);
                    f1[i * 4 + 2] = (__bf16)(aw[i + 2].z * rate + ac[i + 2].z * crate);
                    f1[i * 4 + 3] = (__bf16)(aw[i + 2].w * rate + ac[i + 2].w * crate);
                }
            } else {
                f0 = (bf16x8)0; f1 = (bf16x8)0;
            }
            *(bf16x8*)(An + awr0) = f0;
            *(bf16x8*)(An + awr1) = f1;
            *(bf16x8*)(Wn + wwr0) = wreg0;
            if (w2) *(bf16x8*)(Wn + wwr1) = wreg1;
        }
        // 2) issue global loads for chunk ch+2 (held in regs across compute)
        if (ch + 2 < NCH) {
            const int ko = (ch + 2) * CHK;
            if (val) {
#pragma unroll
                for (int i = 0; i < 4; ++i) {
                    ac[i] = *(const float4*)(cptr + ko + i * 4);
                    aw[i] = *(const float4*)(wptr + ko + i * 4);
                }
            }
            wreg0 = *(const bf16x8*)(wgp0 + ko);
            wreg1 = w2 ? *(const bf16x8*)(wgp1 + ko) : (bf16x8)0;
        }
        // 3) compute chunk ch: 2 A-frags + 5 W-frags -> 10 MFMA
        const char* Ab = smem + (ch % 3) * 8192;
        const char* Wb = smem + 24576 + (ch & 1) * 5120;
        bf16x8 a0 = *(const bf16x8*)(Ab + aoff[0]);
        bf16x8 a1 = *(const bf16x8*)(Ab + aoff[1]);
#pragma unroll
        for (int nt = 0; nt < 5; ++nt) {
            bf16x8 bw = *(const bf16x8*)(Wb + woff[nt]);
            acc[0][nt] = __builtin_amdgcn_mfma_f32_16x16x32_bf16(a0, bw, acc[0][nt], 0, 0, 0);
            acc[1][nt] = __builtin_amdgcn_mfma_f32_16x16x32_bf16(a1, bw, acc[1][nt], 0, 0, 0);
        }
        __syncthreads();
    }

    // ---- epilogue: C/D col = lane&15, row = (lane>>4)*4 + reg  [verified R2-R12] ----
#pragma unroll
    for (int s = 0; s < 2; ++s) {
        const int orow = rowbase + wv * 32 + s * 16 + kgrp * 4;
#pragma unroll
        for (int nt = 0; nt < 5; ++nt) {
            const int col = nt * 16 + l15;
            if (col < NTAGS) {
                const float bias = b_out[col];
#pragma unroll
                for (int i = 0; i < 4; ++i) {
                    out[(size_t)(orow + i) * NTAGS + col] = acc[s][nt][i] + bias;
                }
            }
        }
    }
}

extern "C" void kernel_launch(void* const* d_in, const int* in_sizes, int n_in,
                              void* d_out, int out_size, void* d_ws, size_t ws_size,
                              hipStream_t stream) {
    const float* out_char = (const float*)d_in[0];
    const float* out_word = (const float*)d_in[1];
    const int* word_idx = (const int*)d_in[2];
    const int* is_head = (const int*)d_in[3];
    const int* valid_mask = (const int*)d_in[4];
    const float* W_out = (const float*)d_in[5];
    const float* b_out = (const float*)d_in[6];
    float* out = (float*)d_out;
    __bf16* Wt = (__bf16*)d_ws;  // 80*1024*2 = 160 KB

    prep_w_kernel<<<HH / 64, 256, 0, stream>>>(W_out, Wt);

    const int rows = 16 * TT;  // B*T = 32768
    slu_main<<<rows / MROWS, THREADS, 0, stream>>>(out_char, out_word, word_idx, is_head,
                                                   valid_mask, Wt, b_out, out);
}

// Round 14
// 35.295 us; speedup vs baseline: 1.3368x; 1.3368x over previous
//
#include <hip/hip_runtime.h>
#include <hip/hip_bf16.h>

#define TT 2048
#define HH 1024
#define NTAGS 74
#define NPAD 80
#define CHK 64            // K elements per chunk
#define NCH (HH / CHK)    // 16 chunks
#define MROWS 64          // rows per block
#define THREADS 256
#define NXCD 8

typedef __bf16 bf16x8 __attribute__((ext_vector_type(8)));
typedef float f32x4 __attribute__((ext_vector_type(4)));

// Transpose + convert W_out [1024][74] f32 -> Wt [80][1024] bf16 (pad cols 74..79 = 0)
__global__ __launch_bounds__(256) void prep_w_kernel(const float* __restrict__ W,
                                                     __bf16* __restrict__ Wt) {
    __shared__ float tile[64][80];
    const int k0 = blockIdx.x * 64;
    const int tid = threadIdx.x;
    for (int i = tid; i < 64 * NTAGS; i += 256) {
        int k = i / NTAGS, n = i - k * NTAGS;
        tile[k][n] = W[(k0 + k) * NTAGS + n];
    }
    __syncthreads();
    for (int i = tid; i < NPAD * 64; i += 256) {
        int n = i >> 6, kk = i & 63;
        float v = (n < NTAGS) ? tile[kk][n] : 0.0f;
        Wt[n * HH + k0 + kk] = (__bf16)v;
    }
}

// R14 = R12 (best known: 35.0 us) + ONE change: the per-chunk barrier is a raw
// `s_waitcnt lgkmcnt(0); s_barrier` instead of __syncthreads(). hipcc pads
// __syncthreads with a full vmcnt(0) drain, which retires the chunk ch+2
// global loads issued THIS phase -> every chunk serializes a full memory
// round trip. LDS cross-wave visibility only needs lgkmcnt(0); the held-reg
// loads are wave-local and the compiler inserts their counted vmcnt before
// the blend one phase later. Everything else byte-identical to R12.
__global__ __launch_bounds__(256, 2) void slu_main(const float* __restrict__ out_char,
                                                   const float* __restrict__ out_word,
                                                   const int* __restrict__ word_idx,
                                                   const int* __restrict__ is_head,
                                                   const int* __restrict__ valid_mask,
                                                   const __bf16* __restrict__ Wt,
                                                   const float* __restrict__ b_out,
                                                   float* __restrict__ out) {
    // LDS: A[3] @ 0 (3*8192), W[2] @ 24576 (2*10240) = 45056 B
    __shared__ __align__(16) char smem[45056];
    const int tid = threadIdx.x;
    const int wv = tid >> 6;
    const int lane = tid & 63;
    const int l15 = lane & 15;
    const int kgrp = lane >> 4;

    // ---- XCD-aware bijective swizzle (512 blocks = 8 XCDs x 64 chunks) ----
    const int bid = blockIdx.x;
    const int rb = (bid & (NXCD - 1)) * (512 / NXCD) + (bid >> 3);
    const int rowbase = rb * MROWS;

    // ---- A staging (R5 map): thread covers row rloc=(tid>>2), k-sub q=(tid&3) ----
    const int rloc = tid >> 2;
    const int q = tid & 3;
    const int r = rowbase + rloc;
    const int bq = r >> 11;  // T = 2048
    const int widx = word_idx[r];
    const int val = valid_mask[r];
    const float rt = is_head[r] ? 0.88f : 0.70f;
    const float rate = val ? rt : 0.0f;
    const float crate = val ? (1.0f - rt) : 0.0f;
    const float* cptr = out_char + (size_t)r * HH + q * 16;
    const float* wptr = out_word + ((size_t)bq * TT + widx) * HH + q * 16;
    const int asw = (rloc & 7) << 4;
    const int awr0 = (rloc * 128 + q * 32) ^ asw;
    const int awr1 = (rloc * 128 + q * 32 + 16) ^ asw;

    // ---- W staging (R5 map): 640 16B-units/chunk; thread covers tid, tid+256, (tid<128)?tid+512 ----
    const int wn0 = tid >> 3, wsb = tid & 7;
    const __bf16* wgp0 = Wt + (size_t)wn0 * HH + wsb * 8;
    const __bf16* wgp1 = wgp0 + 32 * HH;
    const __bf16* wgp2 = wgp0 + 64 * HH;
    const int wsw = (wn0 & 7) << 4;
    const int wwr0 = (wn0 * 128 + wsb * 16) ^ wsw;
    const int wwr1 = ((wn0 + 32) * 128 + wsb * 16) ^ wsw;
    const int wwr2 = ((wn0 + 64) * 128 + wsb * 16) ^ wsw;
    const bool w3 = (tid < 128);

    // ---- fragment read offsets (swizzle matches writes; row&7 == l15&7 for A and W) ----
    const int fsw = (l15 & 7) << 4;
    const int arow = wv * 16 + l15;
    int aoff[2], woff[2][5];
#pragma unroll
    for (int s = 0; s < 2; ++s) {
        aoff[s] = (arow * 128 + s * 64 + kgrp * 16) ^ fsw;
#pragma unroll
        for (int nt = 0; nt < 5; ++nt)
            woff[s][nt] = ((nt * 16 + l15) * 128 + s * 64 + kgrp * 16) ^ fsw;
    }

    f32x4 acc[5];
#pragma unroll
    for (int nt = 0; nt < 5; ++nt) acc[nt] = (f32x4){0.f, 0.f, 0.f, 0.f};

    float4 ac[4], aw[4];   // held A loads (chunk ch+2)
    bf16x8 wreg0, wreg1, wreg2;

    // ---- prologue: stage chunk 0 directly; prefetch chunk 1 into regs ----
    {
        float4 c0[4], w0[4];
        if (val) {
#pragma unroll
            for (int i = 0; i < 4; ++i) {
                c0[i] = *(const float4*)(cptr + i * 4);
                w0[i] = *(const float4*)(wptr + i * 4);
            }
        }
        bf16x8 wr0 = *(const bf16x8*)(wgp0);
        bf16x8 wr1 = *(const bf16x8*)(wgp1);
        bf16x8 wr2 = w3 ? *(const bf16x8*)(wgp2) : (bf16x8)0;
        bf16x8 f0, f1;
        if (val) {
#pragma unroll
            for (int i = 0; i < 2; ++i) {
                f0[i * 4 + 0] = (__bf16)(w0[i].x * rate + c0[i].x * crate);
                f0[i * 4 + 1] = (__bf16)(w0[i].y * rate + c0[i].y * crate);
                f0[i * 4 + 2] = (__bf16)(w0[i].z * rate + c0[i].z * crate);
                f0[i * 4 + 3] = (__bf16)(w0[i].w * rate + c0[i].w * crate);
                f1[i * 4 + 0] = (__bf16)(w0[i + 2].x * rate + c0[i + 2].x * crate);
                f1[i * 4 + 1] = (__bf16)(w0[i + 2].y * rate + c0[i + 2].y * crate);
                f1[i * 4 + 2] = (__bf16)(w0[i + 2].z * rate + c0[i + 2].z * crate);
                f1[i * 4 + 3] = (__bf16)(w0[i + 2].w * rate + c0[i + 2].w * crate);
            }
        } else {
            f0 = (bf16x8)0; f1 = (bf16x8)0;
        }
        *(bf16x8*)(smem + awr0) = f0;
        *(bf16x8*)(smem + awr1) = f1;
        *(bf16x8*)(smem + 24576 + wwr0) = wr0;
        *(bf16x8*)(smem + 24576 + wwr1) = wr1;
        if (w3) *(bf16x8*)(smem + 24576 + wwr2) = wr2;
        // prefetch chunk 1 into regs
        if (val) {
#pragma unroll
            for (int i = 0; i < 4; ++i) {
                ac[i] = *(const float4*)(cptr + CHK + i * 4);
                aw[i] = *(const float4*)(wptr + CHK + i * 4);
            }
        }
        wreg0 = *(const bf16x8*)(wgp0 + CHK);
        wreg1 = *(const bf16x8*)(wgp1 + CHK);
        wreg2 = w3 ? *(const bf16x8*)(wgp2 + CHK) : (bf16x8)0;
    }
    __syncthreads();

    // ---- main loop ----
    for (int ch = 0; ch < NCH; ++ch) {
        // 1) commit prefetched chunk ch+1 to LDS
        if (ch + 1 < NCH) {
            char* An = smem + ((ch + 1) % 3) * 8192;
            char* Wn = smem + 24576 + ((ch + 1) & 1) * 10240;
            bf16x8 f0, f1;
            if (val) {
#pragma unroll
                for (int i = 0; i < 2; ++i) {
                    f0[i * 4 + 0] = (__bf16)(aw[i].x * rate + ac[i].x * crate);
                    f0[i * 4 + 1] = (__bf16)(aw[i].y * rate + ac[i].y * crate);
                    f0[i * 4 + 2] = (__bf16)(aw[i].z * rate + ac[i].z * crate);
                    f0[i * 4 + 3] = (__bf16)(aw[i].w * rate + ac[i].w * crate);
                    f1[i * 4 + 0] = (__bf16)(aw[i + 2].x * rate + ac[i + 2].x * crate);
                    f1[i * 4 + 1] = (__bf16)(aw[i + 2].y * rate + ac[i + 2].y * crate);
                    f1[i * 4 + 2] = (__bf16)(aw[i + 2].z * rate + ac[i + 2].z * crate);
                    f1[i * 4 + 3] = (__bf16)(aw[i + 2].w * rate + ac[i + 2].w * crate);
                }
            } else {
                f0 = (bf16x8)0; f1 = (bf16x8)0;
            }
            *(bf16x8*)(An + awr0) = f0;
            *(bf16x8*)(An + awr1) = f1;
            *(bf16x8*)(Wn + wwr0) = wreg0;
            *(bf16x8*)(Wn + wwr1) = wreg1;
            if (w3) *(bf16x8*)(Wn + wwr2) = wreg2;
        }
        // 2) issue global loads for chunk ch+2 (held in regs across compute)
        if (ch + 2 < NCH) {
            const int ko = (ch + 2) * CHK;
            if (val) {
#pragma unroll
                for (int i = 0; i < 4; ++i) {
                    ac[i] = *(const float4*)(cptr + ko + i * 4);
                    aw[i] = *(const float4*)(wptr + ko + i * 4);
                }
            }
            wreg0 = *(const bf16x8*)(wgp0 + ko);
            wreg1 = *(const bf16x8*)(wgp1 + ko);
            wreg2 = w3 ? *(const bf16x8*)(wgp2 + ko) : (bf16x8)0;
        }
        // 3) compute chunk ch
        const char* Ab = smem + (ch % 3) * 8192;
        const char* Wb = smem + 24576 + (ch & 1) * 10240;
#pragma unroll
        for (int s = 0; s < 2; ++s) {
            bf16x8 a = *(const bf16x8*)(Ab + aoff[s]);
#pragma unroll
            for (int nt = 0; nt < 5; ++nt) {
                bf16x8 bw = *(const bf16x8*)(Wb + woff[s][nt]);
                acc[nt] = __builtin_amdgcn_mfma_f32_16x16x32_bf16(a, bw, acc[nt], 0, 0, 0);
            }
        }
        // raw barrier: drain LDS ops only (cross-wave visibility), do NOT
        // drain vmcnt -> the ch+2 global loads stay in flight across phases.
        asm volatile("s_waitcnt lgkmcnt(0)\n\ts_barrier" ::: "memory");
    }

    // ---- epilogue: C/D col = lane&15, row = (lane>>4)*4 + reg  [verified R2-R13] ----
    const int orow = rowbase + wv * 16 + kgrp * 4;
#pragma unroll
    for (int nt = 0; nt < 5; ++nt) {
        const int col = nt * 16 + l15;
        if (col < NTAGS) {
            const float bias = b_out[col];
#pragma unroll
            for (int i = 0; i < 4; ++i) {
                out[(size_t)(orow + i) * NTAGS + col] = acc[nt][i] + bias;
            }
        }
    }
}

extern "C" void kernel_launch(void* const* d_in, const int* in_sizes, int n_in,
                              void* d_out, int out_size, void* d_ws, size_t ws_size,
                              hipStream_t stream) {
    const float* out_char = (const float*)d_in[0];
    const float* out_word = (const float*)d_in[1];
    const int* word_idx = (const int*)d_in[2];
    const int* is_head = (const int*)d_in[3];
    const int* valid_mask = (const int*)d_in[4];
    const float* W_out = (const float*)d_in[5];
    const float* b_out = (const float*)d_in[6];
    float* out = (float*)d_out;
    __bf16* Wt = (__bf16*)d_ws;  // 80*1024*2 = 160 KB

    prep_w_kernel<<<HH / 64, 256, 0, stream>>>(W_out, Wt);

    const int rows = 16 * TT;  // B*T = 32768
    slu_main<<<rows / MROWS, THREADS, 0, stream>>>(out_char, out_word, word_idx, is_head,
                                                   valid_mask, Wt, b_out, out);
}